// Round 2
// baseline (3392.652 us; speedup 1.0000x reference)
//
#include <hip/hip_runtime.h>

typedef __attribute__((ext_vector_type(8))) short   short8;
typedef __attribute__((ext_vector_type(4))) float   float4_;

// ---------------- workspace layout (bytes) ----------------
#define WPACK_OFF   0
#define WPACK_BYTES 786432                    // 1024 rows x 384 k x 2B, A-frag packed
#define HBUF_OFF    786432
#define HBUF_BYTES  524288                    // 4 slots x 16 grp x 64 nu x 16 bw (ull)
#define BIAS_OFF    (HBUF_OFF + HBUF_BYTES)

#define SLOT_ULL 16384                        // ulls per step-slot
#define SENT_ULL 0xFFFFFFFFFFFFFFFFull        // bf16 NaN x4 — unreachable for finite h

__device__ __forceinline__ unsigned short f2bf(float f) {
  unsigned int u = __float_as_uint(f);
  u += 0x7fffu + ((u >> 16) & 1u);            // round-to-nearest-even
  return (unsigned short)(u >> 16);
}

// Pack W = [W_hh | W_ih] into MFMA A-fragment order, bf16.
// frag idx = (((s4*4 + wv)*4 + g)*12 + kt)*64 + lane
// row = g*256 + s4*64 + wv*16 + (lane&15);  k = kt*32 + (lane>>4)*8 + j
__global__ void pack_w(const float* __restrict__ w_ih,
                       const float* __restrict__ w_hh,
                       unsigned short* __restrict__ wpack) {
  int idx = blockIdx.x * blockDim.x + threadIdx.x;
  if (idx >= 49152) return;
  int lane = idx & 63;
  int r1 = idx >> 6;
  int kt = r1 % 12;
  int r2 = r1 / 12;
  int g  = r2 & 3;          // gate
  int r3 = r2 >> 2;
  int wv = r3 & 3;          // wave (n-subtile)
  int s4 = r3 >> 2;         // n-slice 0..3
  int row = g * 256 + s4 * 64 + wv * 16 + (lane & 15);
  int q = lane >> 4;
  short8 o;
#pragma unroll
  for (int j = 0; j < 8; ++j) {
    int kk = kt * 32 + q * 8 + j;             // 0..383
    float v = (kt < 8) ? w_hh[row * 256 + kk]
                       : w_ih[row * 128 + (kk - 256)];
    o[j] = (short)f2bf(v);
  }
  *(short8*)(wpack + (size_t)idx * 8) = o;
}

// hbuf layout: [slot][grp 16][nu 64][bw 16] (ull each = 4 bf16, n = 4nu..4nu+3,
// batch = grp*16+bw). Slot 0 = bf16(h0), slots 1..3 = sentinel. bias = b_ih+b_hh.
__global__ void init_hb(const float* __restrict__ h0,
                        const float* __restrict__ b_ih,
                        const float* __restrict__ b_hh,
                        unsigned long long* __restrict__ hbuf,
                        float* __restrict__ bias) {
  int idx = blockIdx.x * blockDim.x + threadIdx.x;
  if (idx < 16384) {                           // slot 0: seed h0
    int grp = idx >> 10;
    int rem = idx & 1023;
    int nu  = rem >> 4;
    int bw  = rem & 15;
    int b   = grp * 16 + bw;
    unsigned long long v = 0;
#pragma unroll
    for (int e = 0; e < 4; ++e)
      v |= (unsigned long long)f2bf(h0[b * 256 + nu * 4 + e]) << (16 * e);
    hbuf[idx] = v;
  } else if (idx < 65536) {                    // slots 1..3: sentinel
    hbuf[idx] = SENT_ULL;
  } else if (idx < 66560) {
    int j = idx - 65536;
    bias[j] = b_ih[j] + b_hh[j];
  }
}

__device__ __forceinline__ float sigm_(float v) {
  return 1.f / (1.f + __expf(-v));
}
__device__ __forceinline__ float tanh_(float v) {
  return 1.f - 2.f / (__expf(2.f * v) + 1.f);  // robust at +-inf
}

// Grid 64: s4 = id>>4, grp = id&15 -> the 4 blocks of a group are ids
// {grp, grp+16, grp+32, grp+48} == same (id % 8) -> same XCD under the
// round-robin dispatch heuristic (perf-only assumption).
//
// Fully wave-autonomous main loop: NO __syncthreads, NO LDS. Each wave polls
// the entire h_t slot for its batch group (the polled ulls ARE its MFMA
// B-fragments), computes all 4 gates for its 16 n-rows, combines in-register,
// and publishes one 8B agent-scope atomic per thread. The x contribution is
// computed into accx AFTER the h publish — in the shadow of the next
// communication round-trip — from x prefetched one step ahead.
__global__ __launch_bounds__(256, 1) void lstm_main(
    const float* __restrict__ x, const float* __restrict__ c0,
    const unsigned short* __restrict__ wpack, const float* __restrict__ bias,
    unsigned long long* hbuf, float* __restrict__ out) {

  const int tid  = threadIdx.x;
  const int wv   = tid >> 6;       // wave == n-subtile 0..3 (owns all 4 gates)
  const int lane = tid & 63;
  const int q    = lane >> 4;
  const int bl   = lane & 15;

  const int id  = blockIdx.x;
  const int s4  = id >> 4;                  // n-slice 0..3 (64 n each)
  const int grp = id & 15;                  // batch group 0..15

  const int bg = grp * 16 + bl;             // my batch (B-frag column)

  // ---- W fragments in VGPRs/AGPRs: 4 gates x 12 ktiles = 48 frags ----
  short8 wf[48];
  {
    const unsigned short* base =
        wpack + ((size_t)((s4 * 4 + wv) * 48) * 64 + lane) * 8;
#pragma unroll
    for (int f = 0; f < 48; ++f)
      wf[f] = *(const short8*)(base + (size_t)f * 512);
  }
#pragma unroll
  for (int f = 0; f < 48; ++f)
    asm volatile("" : "+v"(wf[f]));

  // bias per gate (acc init); C-rows of my tile = wv*16 + q*4 + r
  float4_ bia[4];
#pragma unroll
  for (int g = 0; g < 4; ++g)
    bia[g] = *(const float4_*)(bias + g * 256 + s4 * 64 + wv * 16 + q * 4);

  // c state: this thread owns n = s4*64 + wv*16 + q*4 + r, batch bg
  float4_ cst = *(const float4_*)(c0 + (size_t)bg * 256 + s4 * 64 + wv * 16 + q * 4);

  // x: per lane needs k = kx*32 + q*8 + [0,8) for kx=0..3 (full row, all waves)
  const float* xrow = x + (size_t)bg * 131072 + q * 8;
  float4_ xr[8];
#pragma unroll
  for (int kx = 0; kx < 4; ++kx) {          // t = 0
    xr[kx * 2]     = *(const float4_*)(xrow + kx * 32);
    xr[kx * 2 + 1] = *(const float4_*)(xrow + kx * 32 + 4);
  }

  // x contribution accumulator for the CURRENT step (bias folded in)
  float4_ accx[4];
  {
    short8 xf[4];
#pragma unroll
    for (int kx = 0; kx < 4; ++kx) {
      short8 v;
#pragma unroll
      for (int e = 0; e < 4; ++e) {
        v[e]     = (short)f2bf(xr[kx * 2][e]);
        v[e + 4] = (short)f2bf(xr[kx * 2 + 1][e]);
      }
      xf[kx] = v;
    }
#pragma unroll
    for (int g = 0; g < 4; ++g) accx[g] = bia[g];
#pragma unroll
    for (int kx = 0; kx < 4; ++kx)
#pragma unroll
      for (int g = 0; g < 4; ++g)
        accx[g] = __builtin_amdgcn_mfma_f32_16x16x32_bf16(wf[g * 12 + 8 + kx], xf[kx], accx[g], 0, 0, 0);
  }
#pragma unroll
  for (int kx = 0; kx < 4; ++kx) {          // prefetch t = 1
    xr[kx * 2]     = *(const float4_*)(xrow + 128 + kx * 32);
    xr[kx * 2 + 1] = *(const float4_*)(xrow + 128 + kx * 32 + 4);
  }

  // hbuf addressing (ull granularity)
  const int    poff   = q * 32 + bl;                                  // poll lane offset
  const size_t gbase  = (size_t)grp * 1024;
  const size_t my_off = gbase + (size_t)(s4 * 16 + wv * 4 + q) * 16 + bl;

  float4_ hf;

#pragma unroll 1
  for (int t = 0; t < 1024; ++t) {
    // ---------- poll h_t: the polled ulls ARE the B-fragments ----------
    unsigned long long p[16];
    {
      unsigned long long* hb = hbuf + (size_t)(t & 3) * SLOT_ULL + gbase + poff;
      for (;;) {
#pragma unroll
        for (int kt = 0; kt < 8; ++kt) {
          p[kt * 2]     = __hip_atomic_load(hb + kt * 128,      __ATOMIC_RELAXED, __HIP_MEMORY_SCOPE_AGENT);
          p[kt * 2 + 1] = __hip_atomic_load(hb + kt * 128 + 16, __ATOMIC_RELAXED, __HIP_MEMORY_SCOPE_AGENT);
        }
        bool ok = true;
#pragma unroll
        for (int i = 0; i < 16; ++i)
          ok &= ((unsigned short)p[i] != 0xFFFFu);  // each ull stored atomically
        if (__all(ok)) break;
        __builtin_amdgcn_s_sleep(1);
      }
    }
    asm volatile("" ::: "memory");   // nothing hoists above the poll

    // reset slot (t+2)&3: holds h_{t-2}, dead (seeing h_t complete implies all
    // waves produced h_t, hence all consumed h_{t-1} and h_{t-2}).
    __hip_atomic_store(hbuf + (size_t)((t + 2) & 3) * SLOT_ULL + my_off,
                       SENT_ULL, __ATOMIC_RELAXED, __HIP_MEMORY_SCOPE_AGENT);

    // ---------- h-part MFMAs straight from poll registers ----------
    float4_ acc[4];
#pragma unroll
    for (int g = 0; g < 4; ++g) acc[g] = accx[g];

#pragma unroll
    for (int kt = 0; kt < 8; ++kt) {
      union { unsigned long long u[2]; short8 v; } uu;
      uu.u[0] = p[kt * 2];
      uu.u[1] = p[kt * 2 + 1];
#pragma unroll
      for (int g = 0; g < 4; ++g)
        acc[g] = __builtin_amdgcn_mfma_f32_16x16x32_bf16(wf[g * 12 + kt], uu.v, acc[g], 0, 0, 0);
    }

    // ---------- in-register combine (thread owns all 4 gates) ----------
    unsigned long long nh = 0;
#pragma unroll
    for (int r = 0; r < 4; ++r) {
      float iv = sigm_(acc[0][r]);
      float fv = sigm_(acc[1][r]);
      float gv = tanh_(acc[2][r]);
      float ov = sigm_(acc[3][r]);
      float cv = fv * cst[r] + iv * gv;
      cst[r] = cv;
      float hv = ov * tanh_(cv);
      hf[r] = hv;
      nh |= (unsigned long long)f2bf(hv) << (16 * r);
    }

    // drain the reset store (and nothing else outstanding) so that
    // reset(slot t+2) is globally visible BEFORE h_{t+1} is published —
    // the one ordering the 4-slot protocol requires.
    asm volatile("s_waitcnt vmcnt(0)" ::: "memory");
    __hip_atomic_store(hbuf + (size_t)((t + 1) & 3) * SLOT_ULL + my_off,
                       nh, __ATOMIC_RELAXED, __HIP_MEMORY_SCOPE_AGENT);

    // ---------- x-part for NEXT step: in the shadow of the comm round-trip ----------
    {
      short8 xf[4];
#pragma unroll
      for (int kx = 0; kx < 4; ++kx) {
        short8 v;
#pragma unroll
        for (int e = 0; e < 4; ++e) {
          v[e]     = (short)f2bf(xr[kx * 2][e]);
          v[e + 4] = (short)f2bf(xr[kx * 2 + 1][e]);
        }
        xf[kx] = v;
      }
#pragma unroll
      for (int g = 0; g < 4; ++g) accx[g] = bia[g];
#pragma unroll
      for (int kx = 0; kx < 4; ++kx)
#pragma unroll
        for (int g = 0; g < 4; ++g)
          accx[g] = __builtin_amdgcn_mfma_f32_16x16x32_bf16(wf[g * 12 + 8 + kx], xf[kx], accx[g], 0, 0, 0);
      // prefetch x(t+2)
      int tn = (t < 1022) ? (t + 2) : 1023;
      const float* xp = xrow + (size_t)tn * 128;
#pragma unroll
      for (int kx = 0; kx < 4; ++kx) {
        xr[kx * 2]     = *(const float4_*)(xp + kx * 32);
        xr[kx * 2 + 1] = *(const float4_*)(xp + kx * 32 + 4);
      }
    }
  }

  // final h (fp32) -> d_out [1,B,H]
  *(float4_*)(out + (size_t)bg * 256 + s4 * 64 + wv * 16 + q * 4) = hf;
}

extern "C" void kernel_launch(void* const* d_in, const int* in_sizes, int n_in,
                              void* d_out, int out_size, void* d_ws, size_t ws_size,
                              hipStream_t stream) {
  (void)in_sizes; (void)n_in; (void)out_size; (void)ws_size;
  const float* x    = (const float*)d_in[0];
  const float* h0   = (const float*)d_in[1];
  const float* c0   = (const float*)d_in[2];
  const float* w_ih = (const float*)d_in[3];
  const float* w_hh = (const float*)d_in[4];
  const float* b_ih = (const float*)d_in[5];
  const float* b_hh = (const float*)d_in[6];

  char* ws = (char*)d_ws;
  unsigned short*     wpack = (unsigned short*)(ws + WPACK_OFF);
  unsigned long long* hbuf  = (unsigned long long*)(ws + HBUF_OFF);
  float*              bias  = (float*)(ws + BIAS_OFF);

  pack_w<<<192, 256, 0, stream>>>(w_ih, w_hh, wpack);
  init_hb<<<260, 256, 0, stream>>>(h0, b_ih, b_hh, hbuf, bias);
  lstm_main<<<64, 256, 0, stream>>>(x, c0, wpack, bias, hbuf, (float*)d_out);
}

// Round 3
// 3309.702 us; speedup vs baseline: 1.0251x; 1.0251x over previous
//
#include <hip/hip_runtime.h>

typedef __attribute__((ext_vector_type(8))) short   short8;
typedef __attribute__((ext_vector_type(4))) float   float4_;

// ---------------- workspace layout (bytes) ----------------
#define WPACK_OFF   0
#define WPACK_BYTES 786432                    // 1024 rows x 384 k x 2B, A-frag packed
#define HBUF_OFF    786432
#define HBUF_BYTES  524288                    // 4 slots x 16 grp x 64 nu x 16 bw (ull)
#define BIAS_OFF    (HBUF_OFF + HBUF_BYTES)

#define SLOT_ULL 16384                        // ulls per step-slot
#define SENT_ULL 0xFFFFFFFFFFFFFFFFull       // bf16 NaN x4 — unreachable for finite h

__device__ __forceinline__ unsigned short f2bf(float f) {
  unsigned int u = __float_as_uint(f);
  u += 0x7fffu + ((u >> 16) & 1u);            // round-to-nearest-even
  return (unsigned short)(u >> 16);
}

// Pack W = [W_hh | W_ih] into MFMA A-fragment order, bf16.
// frag idx = (((s4*4 + wv)*4 + g)*12 + kt)*64 + lane
// row = g*256 + s4*64 + wv*16 + (lane&15);  k = kt*32 + (lane>>4)*8 + j
__global__ void pack_w(const float* __restrict__ w_ih,
                       const float* __restrict__ w_hh,
                       unsigned short* __restrict__ wpack) {
  int idx = blockIdx.x * blockDim.x + threadIdx.x;
  if (idx >= 49152) return;
  int lane = idx & 63;
  int r1 = idx >> 6;
  int kt = r1 % 12;
  int r2 = r1 / 12;
  int g  = r2 & 3;          // gate
  int r3 = r2 >> 2;
  int wv = r3 & 3;          // wave (n-subtile)
  int s4 = r3 >> 2;         // n-slice 0..3
  int row = g * 256 + s4 * 64 + wv * 16 + (lane & 15);
  int q = lane >> 4;
  short8 o;
#pragma unroll
  for (int j = 0; j < 8; ++j) {
    int kk = kt * 32 + q * 8 + j;             // 0..383
    float v = (kt < 8) ? w_hh[row * 256 + kk]
                       : w_ih[row * 128 + (kk - 256)];
    o[j] = (short)f2bf(v);
  }
  *(short8*)(wpack + (size_t)idx * 8) = o;
}

// hbuf layout: [slot][grp 16][nu 64][bw 16] (ull each = 4 bf16, n = 4nu..4nu+3,
// batch = grp*16+bw). Slot 0 = bf16(h0), slots 1..3 = sentinel. bias = b_ih+b_hh.
__global__ void init_hb(const float* __restrict__ h0,
                        const float* __restrict__ b_ih,
                        const float* __restrict__ b_hh,
                        unsigned long long* __restrict__ hbuf,
                        float* __restrict__ bias) {
  int idx = blockIdx.x * blockDim.x + threadIdx.x;
  if (idx < 16384) {                           // slot 0: seed h0
    int grp = idx >> 10;
    int rem = idx & 1023;
    int nu  = rem >> 4;
    int bw  = rem & 15;
    int b   = grp * 16 + bw;
    unsigned long long v = 0;
#pragma unroll
    for (int e = 0; e < 4; ++e)
      v |= (unsigned long long)f2bf(h0[b * 256 + nu * 4 + e]) << (16 * e);
    hbuf[idx] = v;
  } else if (idx < 65536) {                    // slots 1..3: sentinel
    hbuf[idx] = SENT_ULL;
  } else if (idx < 66560) {
    int j = idx - 65536;
    bias[j] = b_ih[j] + b_hh[j];
  }
}

__device__ __forceinline__ float sigm_(float v) {
  return 1.f / (1.f + __expf(-v));
}
__device__ __forceinline__ float tanh_(float v) {
  return 1.f - 2.f / (__expf(2.f * v) + 1.f);  // robust at +-inf
}

// One step of the recurrence. T = step index. XC = xr buffer holding x(T+1)
// (consumed in the tail to build accx for step T+1); XN = buffer that receives
// the early-issued loads of x(T+2).
//
// Ordering contract (no waitcnt before publish!):
//  - reset slot (T+3)&3 = (T-1)&3 holds h_{T-1}, dead: detecting h_T complete
//    implies all 16 producer waves published h_T, hence all detected h_{T-1}.
//  - that slot is next written with h_{T+3}, polled only after h_{T+2} is
//    detected; my step-(T+1) poll's vmcnt(0) retires this reset store before I
//    publish h_{T+2}, which gates h_{T+3} polling. Visibility ordering holds
//    with no explicit drain on the publish path.
#define STEP(T, XC, XN)                                                         \
  {                                                                             \
    unsigned long long p[16];                                                   \
    {                                                                           \
      unsigned long long* hb = hbuf + (size_t)((T) & 3) * SLOT_ULL + gbase + poff; \
      for (;;) {                                                                \
        _Pragma("unroll")                                                       \
        for (int kt = 0; kt < 8; ++kt) {                                        \
          p[kt * 2]     = __hip_atomic_load(hb + kt * 128,      __ATOMIC_RELAXED, __HIP_MEMORY_SCOPE_AGENT); \
          p[kt * 2 + 1] = __hip_atomic_load(hb + kt * 128 + 16, __ATOMIC_RELAXED, __HIP_MEMORY_SCOPE_AGENT); \
        }                                                                       \
        bool ok = true;                                                         \
        _Pragma("unroll")                                                       \
        for (int i = 0; i < 16; ++i)                                            \
          ok &= ((unsigned short)p[i] != 0xFFFFu);                              \
        if (__all(ok)) break;                                                   \
        __builtin_amdgcn_s_sleep(1);                                            \
      }                                                                         \
    }                                                                           \
    asm volatile("" ::: "memory");                                              \
    __hip_atomic_store(hbuf + (size_t)(((T) + 3) & 3) * SLOT_ULL + my_off,      \
                       SENT_ULL, __ATOMIC_RELAXED, __HIP_MEMORY_SCOPE_AGENT);   \
    {  /* early x(T+2) issue: hides HBM latency under MFMA+combine+tail */      \
      int tn = ((T) < 1022) ? (T) + 2 : 1023;                                   \
      const float* xp = xrow + (size_t)tn * 128;                                \
      _Pragma("unroll")                                                         \
      for (int kx = 0; kx < 4; ++kx) {                                          \
        XN[kx * 2]     = *(const float4_*)(xp + kx * 32);                       \
        XN[kx * 2 + 1] = *(const float4_*)(xp + kx * 32 + 4);                   \
      }                                                                         \
    }                                                                           \
    float4_ acc[4];                                                             \
    _Pragma("unroll")                                                           \
    for (int g = 0; g < 4; ++g) acc[g] = accx[g];                               \
    _Pragma("unroll")                                                           \
    for (int kt = 0; kt < 8; ++kt) {                                            \
      union { unsigned long long u[2]; short8 v; } uu;                          \
      uu.u[0] = p[kt * 2];                                                      \
      uu.u[1] = p[kt * 2 + 1];                                                  \
      _Pragma("unroll")                                                         \
      for (int g = 0; g < 4; ++g)                                               \
        acc[g] = __builtin_amdgcn_mfma_f32_16x16x32_bf16(wf[g * 12 + kt], uu.v, acc[g], 0, 0, 0); \
    }                                                                           \
    unsigned long long nh = 0;                                                  \
    _Pragma("unroll")                                                           \
    for (int r = 0; r < 4; ++r) {                                               \
      float iv = sigm_(acc[0][r]);                                              \
      float fv = sigm_(acc[1][r]);                                              \
      float gv = tanh_(acc[2][r]);                                              \
      float ov = sigm_(acc[3][r]);                                              \
      float cv = fv * cst[r] + iv * gv;                                         \
      cst[r] = cv;                                                              \
      float hv = ov * tanh_(cv);                                                \
      hf[r] = hv;                                                               \
      nh |= (unsigned long long)f2bf(hv) << (16 * r);                           \
    }                                                                           \
    __hip_atomic_store(hbuf + (size_t)(((T) + 1) & 3) * SLOT_ULL + my_off,      \
                       nh, __ATOMIC_RELAXED, __HIP_MEMORY_SCOPE_AGENT);         \
    asm volatile("" ::: "memory");                                              \
    {  /* x-part for step T+1 in the comm shadow: consume XC = x(T+1) */        \
      short8 xf[4];                                                             \
      _Pragma("unroll")                                                         \
      for (int kx = 0; kx < 4; ++kx) {                                          \
        short8 v;                                                               \
        _Pragma("unroll")                                                       \
        for (int e = 0; e < 4; ++e) {                                           \
          v[e]     = (short)f2bf(XC[kx * 2][e]);                                \
          v[e + 4] = (short)f2bf(XC[kx * 2 + 1][e]);                            \
        }                                                                       \
        xf[kx] = v;                                                             \
      }                                                                         \
      _Pragma("unroll")                                                         \
      for (int g = 0; g < 4; ++g) accx[g] = bia[g];                             \
      _Pragma("unroll")                                                         \
      for (int kx = 0; kx < 4; ++kx)                                            \
        _Pragma("unroll")                                                       \
        for (int g = 0; g < 4; ++g)                                             \
          accx[g] = __builtin_amdgcn_mfma_f32_16x16x32_bf16(wf[g * 12 + 8 + kx], xf[kx], accx[g], 0, 0, 0); \
    }                                                                           \
  }

// Grid 64: s4 = id>>4, grp = id&15 -> the 4 blocks of a group are ids
// {grp, grp+16, grp+32, grp+48} == same (id % 8) -> same XCD under the
// round-robin dispatch heuristic (perf-only assumption).
__global__ __launch_bounds__(256, 1) void lstm_main(
    const float* __restrict__ x, const float* __restrict__ c0,
    const unsigned short* __restrict__ wpack, const float* __restrict__ bias,
    unsigned long long* hbuf, float* __restrict__ out) {

  const int tid  = threadIdx.x;
  const int wv   = tid >> 6;       // wave == n-subtile 0..3 (owns all 4 gates)
  const int lane = tid & 63;
  const int q    = lane >> 4;
  const int bl   = lane & 15;

  const int id  = blockIdx.x;
  const int s4  = id >> 4;                  // n-slice 0..3 (64 n each)
  const int grp = id & 15;                  // batch group 0..15

  const int bg = grp * 16 + bl;             // my batch (B-frag column)

  // ---- W fragments in registers: 4 gates x 12 ktiles = 48 frags ----
  short8 wf[48];
  {
    const unsigned short* base =
        wpack + ((size_t)((s4 * 4 + wv) * 48) * 64 + lane) * 8;
#pragma unroll
    for (int f = 0; f < 48; ++f)
      wf[f] = *(const short8*)(base + (size_t)f * 512);
  }
#pragma unroll
  for (int f = 0; f < 48; ++f)
    asm volatile("" : "+v"(wf[f]));

  // bias per gate (acc init); C-rows of my tile = wv*16 + q*4 + r
  float4_ bia[4];
#pragma unroll
  for (int g = 0; g < 4; ++g)
    bia[g] = *(const float4_*)(bias + g * 256 + s4 * 64 + wv * 16 + q * 4);

  // c state: this thread owns n = s4*64 + wv*16 + q*4 + r, batch bg
  float4_ cst = *(const float4_*)(c0 + (size_t)bg * 256 + s4 * 64 + wv * 16 + q * 4);

  // x: per lane needs k = kx*32 + q*8 + [0,8) for kx=0..3
  const float* xrow = x + (size_t)bg * 131072 + q * 8;

  float4_ xrA[8], xrB[8];
#pragma unroll
  for (int kx = 0; kx < 4; ++kx) {          // x(0)
    xrA[kx * 2]     = *(const float4_*)(xrow + kx * 32);
    xrA[kx * 2 + 1] = *(const float4_*)(xrow + kx * 32 + 4);
  }

  // accx(0) (bias folded in)
  float4_ accx[4];
  {
    short8 xf[4];
#pragma unroll
    for (int kx = 0; kx < 4; ++kx) {
      short8 v;
#pragma unroll
      for (int e = 0; e < 4; ++e) {
        v[e]     = (short)f2bf(xrA[kx * 2][e]);
        v[e + 4] = (short)f2bf(xrA[kx * 2 + 1][e]);
      }
      xf[kx] = v;
    }
#pragma unroll
    for (int g = 0; g < 4; ++g) accx[g] = bia[g];
#pragma unroll
    for (int kx = 0; kx < 4; ++kx)
#pragma unroll
      for (int g = 0; g < 4; ++g)
        accx[g] = __builtin_amdgcn_mfma_f32_16x16x32_bf16(wf[g * 12 + 8 + kx], xf[kx], accx[g], 0, 0, 0);
  }
#pragma unroll
  for (int kx = 0; kx < 4; ++kx) {          // x(1) -> xrA (consumed at t=0 tail)
    xrA[kx * 2]     = *(const float4_*)(xrow + 128 + kx * 32);
    xrA[kx * 2 + 1] = *(const float4_*)(xrow + 128 + kx * 32 + 4);
  }

  // hbuf addressing (ull granularity)
  const int    poff   = q * 32 + bl;
  const size_t gbase  = (size_t)grp * 1024;
  const size_t my_off = gbase + (size_t)(s4 * 16 + wv * 4 + q) * 16 + bl;

  float4_ hf;

#pragma unroll 1
  for (int t = 0; t < 1024; t += 2) {
    STEP(t,     xrA, xrB)     // consumes xrA = x(t+1), issues x(t+2) -> xrB
    STEP(t + 1, xrB, xrA)     // consumes xrB = x(t+2), issues x(t+3) -> xrA
  }

  // final h (fp32) -> d_out [1,B,H]
  *(float4_*)(out + (size_t)bg * 256 + s4 * 64 + wv * 16 + q * 4) = hf;
}

extern "C" void kernel_launch(void* const* d_in, const int* in_sizes, int n_in,
                              void* d_out, int out_size, void* d_ws, size_t ws_size,
                              hipStream_t stream) {
  (void)in_sizes; (void)n_in; (void)out_size; (void)ws_size;
  const float* x    = (const float*)d_in[0];
  const float* h0   = (const float*)d_in[1];
  const float* c0   = (const float*)d_in[2];
  const float* w_ih = (const float*)d_in[3];
  const float* w_hh = (const float*)d_in[4];
  const float* b_ih = (const float*)d_in[5];
  const float* b_hh = (const float*)d_in[6];

  char* ws = (char*)d_ws;
  unsigned short*     wpack = (unsigned short*)(ws + WPACK_OFF);
  unsigned long long* hbuf  = (unsigned long long*)(ws + HBUF_OFF);
  float*              bias  = (float*)(ws + BIAS_OFF);

  pack_w<<<192, 256, 0, stream>>>(w_ih, w_hh, wpack);
  init_hb<<<260, 256, 0, stream>>>(h0, b_ih, b_hh, hbuf, bias);
  lstm_main<<<64, 256, 0, stream>>>(x, c0, wpack, bias, hbuf, (float*)d_out);
}

// Round 4
// 2629.490 us; speedup vs baseline: 1.2902x; 1.2587x over previous
//
#include <hip/hip_runtime.h>

typedef __attribute__((ext_vector_type(8))) short   short8;
typedef __attribute__((ext_vector_type(4))) float   float4_;

// ---------------- workspace layout (bytes) ----------------
#define WPACK_OFF   0
#define WPACK_BYTES 786432                    // whh frags 512KB + wih frags 256KB
#define HBUF_OFF    786432
#define HBUF_BYTES  524288                    // 4 slots x 16 grp x 64 nu x 16 bw (ull)
#define BIAS_OFF    (HBUF_OFF + HBUF_BYTES)

#define SLOT_ULL 16384                        // ulls per step-slot
#define SENT_ULL 0xFFFFFFFFFFFFFFFFull        // bf16 NaN x4 — unreachable for finite h

__device__ __forceinline__ unsigned short f2bf(float f) {
  unsigned int u = __float_as_uint(f);
  u += 0x7fffu + ((u >> 16) & 1u);            // round-to-nearest-even
  return (unsigned short)(u >> 16);
}

// Pack W into MFMA A-fragment order, bf16. Two regions:
// region0 (idx<32768): W_hh frags f = ((half*8+wv)*4+g)*8+kt, kt=0..7 (k=h 0..255)
// region1 (idx>=32768): W_ih frags f = ((half*8+wv)*4+g)*4+kx, kx=0..3 (k=x 0..127)
// row = g*256 + half*128 + wv*16 + (lane&15); k = ktile*32 + (lane>>4)*8 + j
__global__ void pack_w(const float* __restrict__ w_ih,
                       const float* __restrict__ w_hh,
                       unsigned short* __restrict__ wpack) {
  int idx = blockIdx.x * blockDim.x + threadIdx.x;
  if (idx >= 49152) return;
  int lane = idx & 63;
  int q = lane >> 4;
  short8 o;
  if (idx < 32768) {                          // W_hh
    int f  = idx >> 6;                        // 0..511
    int kt = f & 7, r = f >> 3;
    int g  = r & 3; r >>= 2;
    int wv = r & 7, hf2 = r >> 3;
    int row = g * 256 + hf2 * 128 + wv * 16 + (lane & 15);
#pragma unroll
    for (int j = 0; j < 8; ++j)
      o[j] = (short)f2bf(w_hh[row * 256 + kt * 32 + q * 8 + j]);
  } else {                                    // W_ih
    int f  = (idx - 32768) >> 6;              // 0..255
    int kx = f & 3, r = f >> 2;
    int g  = r & 3; r >>= 2;
    int wv = r & 7, hf2 = r >> 3;
    int row = g * 256 + hf2 * 128 + wv * 16 + (lane & 15);
#pragma unroll
    for (int j = 0; j < 8; ++j)
      o[j] = (short)f2bf(w_ih[row * 128 + kx * 32 + q * 8 + j]);
  }
  *(short8*)(wpack + (size_t)idx * 8) = o;
}

// hbuf layout: [slot][grp 16][nu 64][bw 16] (ull = 4 bf16, n = 4nu..4nu+3,
// batch = grp*16+bw). Slot 0 = bf16(h0), slots 1..3 = sentinel. bias = b_ih+b_hh.
__global__ void init_hb(const float* __restrict__ h0,
                        const float* __restrict__ b_ih,
                        const float* __restrict__ b_hh,
                        unsigned long long* __restrict__ hbuf,
                        float* __restrict__ bias) {
  int idx = blockIdx.x * blockDim.x + threadIdx.x;
  if (idx < 16384) {                           // slot 0: seed h0
    int grp = idx >> 10;
    int rem = idx & 1023;
    int nu  = rem >> 4;
    int bw  = rem & 15;
    int b   = grp * 16 + bw;
    unsigned long long v = 0;
#pragma unroll
    for (int e = 0; e < 4; ++e)
      v |= (unsigned long long)f2bf(h0[b * 256 + nu * 4 + e]) << (16 * e);
    hbuf[idx] = v;
  } else if (idx < 65536) {                    // slots 1..3: sentinel
    hbuf[idx] = SENT_ULL;
  } else if (idx < 66560) {
    int j = idx - 65536;
    bias[j] = b_ih[j] + b_hh[j];
  }
}

__device__ __forceinline__ float sigm_(float v) {
  return 1.f / (1.f + __expf(-v));
}
__device__ __forceinline__ float tanh_(float v) {
  return 1.f - 2.f / (__expf(2.f * v) + 1.f);  // robust at +-inf
}

// Raw barrier: LDS visibility only (lgkmcnt). Deliberately NO vmcnt drain —
// in-flight x prefetches / publish-acks must not stall the barrier. Global
// ordering for the slot protocol is carried by the pollers' poll-loop
// vmcnt(0) + barrier ARRIVAL ordering (see reset comment in the loop).
#define BAR() do { asm volatile("s_waitcnt lgkmcnt(0)" ::: "memory"); \
                   __builtin_amdgcn_s_barrier();                      \
                   asm volatile("" ::: "memory"); } while (0)

// Grid 32: half = id>>4 (n-half 0/1), grp = id&15. The 2 blocks of a group are
// ids {grp, grp+16} == same (id%8) -> same XCD under round-robin (perf-only).
//
// Block: 512 thr / 8 waves. Wave wv owns n = half*128 + wv*16 + [0,16), all 4
// gates, for 16 batches. W_hh in registers (32 frags). W_ih + x B-frags + h
// B-frags in LDS. Waves 0-3 poll exactly one foreign k-tile each (2 ulls/lane
// = 4KB/block/round — minimum possible); polled ulls ARE the B-frags. Self
// half never round-trips through MALL (register hull -> LDS). Waves 4-7
// produce the shared x B-frags. One raw barrier per step.
__global__ __launch_bounds__(512, 1) void lstm_main(
    const float* __restrict__ x, const float* __restrict__ c0,
    const unsigned short* __restrict__ wpack, const float* __restrict__ bias,
    unsigned long long* hbuf, float* __restrict__ out) {

  const int tid  = threadIdx.x;
  const int wv   = tid >> 6;       // wave 0..7
  const int lane = tid & 63;
  const int q    = lane >> 4;
  const int bl   = lane & 15;

  const int id   = blockIdx.x;
  const int half = id >> 4;                 // n-half 0..1 (128 n each)
  const int grp  = id & 15;                 // batch group 0..15

  const int bg = grp * 16 + bl;             // my batch (B-frag column)

  // LDS: W_ih frags (128KB) + h-frag dbuf (16KB) + x-frag dbuf (8KB)
  __shared__ short8 wih[8][4][4][64];       // [wv][gate][kx][lane]
  __shared__ short8 hbf[2][8][64];          // [parity][ktile][lane]
  __shared__ short8 xfb[2][4][64];          // [parity][kx][lane]

  // ---- W_ih -> LDS (linear copy; global layout == LDS layout) ----
  {
    const short8* src = (const short8*)wpack + 32768 + half * 8192;
    short8* dst = &wih[0][0][0][0];
#pragma unroll
    for (int it = 0; it < 16; ++it)
      dst[it * 512 + tid] = src[it * 512 + tid];
  }

  // ---- W_hh fragments in registers: 4 gates x 8 ktiles = 32 frags ----
  short8 wf[32];
  {
    const unsigned short* base =
        wpack + ((size_t)((half * 8 + wv) * 32) * 64 + lane) * 8;
#pragma unroll
    for (int f = 0; f < 32; ++f)
      wf[f] = *(const short8*)(base + (size_t)f * 512);
  }
#pragma unroll
  for (int f = 0; f < 32; ++f)
    asm volatile("" : "+v"(wf[f]));

  // bias per gate; C-rows of my tile = q*4 + r
  const int n0 = half * 128 + wv * 16 + q * 4;
  float4_ bia[4];
#pragma unroll
  for (int g = 0; g < 4; ++g)
    bia[g] = *(const float4_*)(bias + g * 256 + n0);

  // c state
  float4_ cst = *(const float4_*)(c0 + (size_t)bg * 256 + n0);

  // my produced h chunk (4 bf16 = 1 ull)
  const size_t gbase  = (size_t)grp * 1024;
  const size_t my_off = gbase + (size_t)(half * 32 + wv * 4 + q) * 16 + bl;
  unsigned long long hull = hbuf[my_off];   // slot 0 = bf16(h0)

  __syncthreads();                          // wih visible (prologue only)

  // ---- accx(0) = bias + W_ih x(0): local convert, wih from LDS ----
  const float* xrow = x + (size_t)bg * 131072 + q * 8;
  float4_ accx[4];
  {
    short8 xl[4];
#pragma unroll
    for (int kx = 0; kx < 4; ++kx) {
      float4_ a = *(const float4_*)(xrow + kx * 32);
      float4_ b = *(const float4_*)(xrow + kx * 32 + 4);
      short8 v;
#pragma unroll
      for (int e = 0; e < 4; ++e) { v[e] = (short)f2bf(a[e]); v[e + 4] = (short)f2bf(b[e]); }
      xl[kx] = v;
    }
#pragma unroll
    for (int g = 0; g < 4; ++g) accx[g] = bia[g];
#pragma unroll
    for (int kx = 0; kx < 4; ++kx) {
#pragma unroll
      for (int g = 0; g < 4; ++g) {
        short8 wfr = wih[wv][g][kx][lane];
        accx[g] = __builtin_amdgcn_mfma_f32_16x16x32_bf16(wfr, xl[kx], accx[g], 0, 0, 0);
      }
    }
  }

  // waves 4-7: produce xfb[1] = x(1) frags (consumed at tail(0) -> accx(1))
  const int myk = wv - 4;
  float4_ xr0, xr1;
  if (wv >= 4) {
    const float* xp = x + (size_t)bg * 131072 + 128 + myk * 32 + q * 8;
    float4_ a = *(const float4_*)xp;
    float4_ b = *(const float4_*)(xp + 4);
    short8 v;
#pragma unroll
    for (int e = 0; e < 4; ++e) { v[e] = (short)f2bf(a[e]); v[e + 4] = (short)f2bf(b[e]); }
    xfb[1][myk][lane] = v;
  }

  float4_ hf;

#pragma unroll 1
  for (int t = 0; t < 1024; ++t) {
    const int par = t & 1;

    // ---- publish self hull into hbf[par] (LDS only; no MALL round-trip) ----
    {
      int m = 4 * wv + q;                         // 0..31
      int kt_s = half * 4 + (m >> 3);
      int lidx = ((m & 7) >> 1) * 16 + bl;
      ((unsigned long long*)&hbf[par][kt_s][lidx])[q & 1] = hull;
    }

    // ---- waves 0-3: poll ONE foreign ktile (2 ulls/lane); frag = poll regs ----
    if (wv < 4) {
      const int kt_f = (1 - half) * 4 + wv;
      unsigned long long* hb =
          hbuf + (size_t)(t & 3) * SLOT_ULL + gbase + (size_t)kt_f * 128 + q * 32 + bl;
      unsigned long long p0, p1;
      for (;;) {
        p0 = __hip_atomic_load(hb,      __ATOMIC_RELAXED, __HIP_MEMORY_SCOPE_AGENT);
        p1 = __hip_atomic_load(hb + 16, __ATOMIC_RELAXED, __HIP_MEMORY_SCOPE_AGENT);
        bool ok = ((unsigned short)p0 != 0xFFFFu) & ((unsigned short)p1 != 0xFFFFu);
        if (__all(ok)) break;
        __builtin_amdgcn_s_sleep(1);
      }
      asm volatile("" ::: "memory");              // nothing hoists above the poll
      union { unsigned long long u[2]; short8 v; } uu;
      uu.u[0] = p0; uu.u[1] = p1;
      hbf[par][kt_f][lane] = uu.v;

      // Reset slot (t+3)&3 (holds dead h_{t-1}; h_t detected => other block
      // consumed it). Ordering: this store drains at MY poll(t+1)'s vmcnt(0),
      // before I arrive at barrier(t+1); every thread's h_{t+3} publish is
      // post-release of barrier(t+2) > my arrival => reset precedes ALL
      // h_{t+3} publishes into this slot. Pollers cover all 512 own-half ulls.
      unsigned long long* rp =
          hbuf + (size_t)((t + 3) & 3) * SLOT_ULL + gbase +
          (size_t)(half * 32 + wv * 8 + q * 2) * 16 + bl;
      __hip_atomic_store(rp,      SENT_ULL, __ATOMIC_RELAXED, __HIP_MEMORY_SCOPE_AGENT);
      __hip_atomic_store(rp + 16, SENT_ULL, __ATOMIC_RELAXED, __HIP_MEMORY_SCOPE_AGENT);
    }

    BAR();                                        // hbf[par] complete

    // waves 4-7: issue x(t+2) loads now (consumed at tail; ~full MFMA+combine
    // phase of latency hiding; never drained by a barrier)
    if (wv >= 4) {
      int tn = (t < 1021) ? t + 2 : 1023;
      const float* xp = x + (size_t)bg * 131072 + (size_t)tn * 128 + myk * 32 + q * 8;
      xr0 = *(const float4_*)xp;
      xr1 = *(const float4_*)(xp + 4);
    }

    // ---- h-part: 8 ktiles from LDS, 32 MFMAs ----
    float4_ acc[4];
#pragma unroll
    for (int g = 0; g < 4; ++g) acc[g] = accx[g];
#pragma unroll
    for (int kt = 0; kt < 8; ++kt) {
      short8 bf = hbf[par][kt][lane];
#pragma unroll
      for (int g = 0; g < 4; ++g)
        acc[g] = __builtin_amdgcn_mfma_f32_16x16x32_bf16(wf[g * 8 + kt], bf, acc[g], 0, 0, 0);
    }

    // ---- in-register combine (thread owns all 4 gates) ----
    unsigned long long nh = 0;
#pragma unroll
    for (int r = 0; r < 4; ++r) {
      float iv = sigm_(acc[0][r]);
      float fv = sigm_(acc[1][r]);
      float gv = tanh_(acc[2][r]);
      float ov = sigm_(acc[3][r]);
      float cv = fv * cst[r] + iv * gv;
      cst[r] = cv;
      float hv = ov * tanh_(cv);
      hf[r] = hv;
      nh |= (unsigned long long)f2bf(hv) << (16 * r);
    }
    hull = nh;
    __hip_atomic_store(hbuf + (size_t)((t + 1) & 3) * SLOT_ULL + my_off,
                       nh, __ATOMIC_RELAXED, __HIP_MEMORY_SCOPE_AGENT);

    // ---- tail (comm shadow): x-part for step t+1 ----
    {
      const int pc = (t + 1) & 1;                 // xfb[pc] holds x(t+1)
      if (wv >= 4) {                              // write xfb[par] = x(t+2)
        short8 v;
#pragma unroll
        for (int e = 0; e < 4; ++e) { v[e] = (short)f2bf(xr0[e]); v[e + 4] = (short)f2bf(xr1[e]); }
        xfb[par][myk][lane] = v;
      }
#pragma unroll
      for (int g = 0; g < 4; ++g) accx[g] = bia[g];
#pragma unroll
      for (int kx = 0; kx < 4; ++kx) {
        short8 xv = xfb[pc][kx][lane];
#pragma unroll
        for (int g = 0; g < 4; ++g) {
          short8 wfr = wih[wv][g][kx][lane];
          accx[g] = __builtin_amdgcn_mfma_f32_16x16x32_bf16(wfr, xv, accx[g], 0, 0, 0);
        }
      }
    }
  }

  // final h (fp32) -> d_out [1,B,H]
  *(float4_*)(out + (size_t)bg * 256 + n0) = hf;
}

extern "C" void kernel_launch(void* const* d_in, const int* in_sizes, int n_in,
                              void* d_out, int out_size, void* d_ws, size_t ws_size,
                              hipStream_t stream) {
  (void)in_sizes; (void)n_in; (void)out_size; (void)ws_size;
  const float* x    = (const float*)d_in[0];
  const float* h0   = (const float*)d_in[1];
  const float* c0   = (const float*)d_in[2];
  const float* w_ih = (const float*)d_in[3];
  const float* w_hh = (const float*)d_in[4];
  const float* b_ih = (const float*)d_in[5];
  const float* b_hh = (const float*)d_in[6];

  char* ws = (char*)d_ws;
  unsigned short*     wpack = (unsigned short*)(ws + WPACK_OFF);
  unsigned long long* hbuf  = (unsigned long long*)(ws + HBUF_OFF);
  float*              bias  = (float*)(ws + BIAS_OFF);

  pack_w<<<192, 256, 0, stream>>>(w_ih, w_hh, wpack);
  init_hb<<<260, 256, 0, stream>>>(h0, b_ih, b_hh, hbuf, bias);
  lstm_main<<<32, 512, 0, stream>>>(x, c0, wpack, bias, hbuf, (float*)d_out);
}